// Round 1
// baseline (1170.508 us; speedup 1.0000x reference)
//
#include <hip/hip_runtime.h>

// Problem constants (from reference): D_IN = 128 outputs/row, N_REL = 64.
constexpr int D = 128;
constexpr int R = 64;

// Zero the counts region: first 64 floats (16 float4) of each 128-float row.
__global__ void zero_counts_kernel(float4* __restrict__ out, long total_q) {
    long i = (long)blockIdx.x * blockDim.x + threadIdx.x;
    long stride = (long)gridDim.x * blockDim.x;
    float4 z = make_float4(0.f, 0.f, 0.f, 0.f);
    for (; i < total_q; i += stride) {
        long row = i >> 4;        // 16 float4 of counts per row
        long q = i & 15;
        out[row * 32 + q] = z;    // row stride = 128 floats = 32 float4
    }
}

// Per-edge scatter: counts[src][rel] += 1, stored at out[src*128 + rel].
__global__ void count_kernel(const int* __restrict__ src,
                             const int* __restrict__ et,
                             float* __restrict__ out, int n_edge) {
    int i = blockIdx.x * blockDim.x + threadIdx.x;
    int stride = gridDim.x * blockDim.x;
    for (; i < n_edge; i += stride) {
        int s = src[i];
        int t = et[i];
        atomicAdd(out + (size_t)s * D + t, 1.0f);
    }
}

// One wave (64 lanes) per entity. Lane l keeps rel[:, l] and rel[:, l+64] in
// registers (128 VGPR); counts read coalesced + shfl-broadcast.
// In-place safe: the wave reads its row's counts before writing the row.
__global__ void finalize_kernel(float* __restrict__ out,
                                const float* __restrict__ rel,
                                const float* __restrict__ bias,
                                int n_ent) {
    const int lane = (int)(threadIdx.x & 63);
    const int wid = (int)((blockIdx.x * blockDim.x + threadIdx.x) >> 6);
    const int nw = (int)((gridDim.x * blockDim.x) >> 6);

    float ra[R], rb[R];
#pragma unroll
    for (int r = 0; r < R; ++r) {
        ra[r] = rel[r * D + lane];
        rb[r] = rel[r * D + 64 + lane];
    }
    const float ba = bias[lane];
    const float bb = bias[64 + lane];

    for (int e = wid; e < n_ent; e += nw) {
        float* row = out + (size_t)e * D;
        float cl = row[lane];          // lane l holds count[e][l]
        // deg = sum of 64 counts (butterfly reduce)
        float deg = cl;
#pragma unroll
        for (int off = 32; off; off >>= 1) deg += __shfl_xor(deg, off);

        float a0 = 0.f, a1 = 0.f;
#pragma unroll
        for (int r = 0; r < R; ++r) {
            float c = __shfl(cl, r);   // broadcast count r to all lanes
            a0 = fmaf(c, ra[r], a0);
            a1 = fmaf(c, rb[r], a1);
        }
        float s = 1.0f / (deg + 1.0f);
        float y0 = fmaf(a0, s, ba);
        float y1 = fmaf(a1, s, bb);
        row[lane] = fmaxf(y0, 0.f);
        row[64 + lane] = fmaxf(y1, 0.f);
    }
}

extern "C" void kernel_launch(void* const* d_in, const int* in_sizes, int n_in,
                              void* d_out, int out_size, void* d_ws, size_t ws_size,
                              hipStream_t stream) {
    // inputs: 0=num_entities(scalar), 1=source, 2=edge_type, 3=rel_emb, 4=bias
    const int* src = (const int*)d_in[1];
    const int* et = (const int*)d_in[2];
    const float* rel = (const float*)d_in[3];
    const float* bias = (const float*)d_in[4];
    float* out = (float*)d_out;

    const int n_edge = in_sizes[1];
    const int n_ent = out_size / D;

    zero_counts_kernel<<<2048, 256, 0, stream>>>((float4*)out, (long)n_ent * 16);
    count_kernel<<<4096, 256, 0, stream>>>(src, et, out, n_edge);
    finalize_kernel<<<2048, 256, 0, stream>>>(out, rel, bias, n_ent);
}

// Round 2
// 810.653 us; speedup vs baseline: 1.4439x; 1.4439x over previous
//
#include <hip/hip_runtime.h>

// Problem constants (from reference): D_IN = 128 outputs/row, N_REL = 64.
constexpr int D = 128;
constexpr int R = 64;

// Counts are packed u8, 4 per u32, in the first 16 u32 words of each
// 512-byte output row (race-free in-place scratch: entity e's counts live
// inside row e, and the finalize wave reads them before overwriting row e).

// Zero the packed-counts region: first 4 float4 (64 B) of each row.
__global__ void zero_counts_kernel(float4* __restrict__ out, long total_q) {
    long i = (long)blockIdx.x * blockDim.x + threadIdx.x;
    long stride = (long)gridDim.x * blockDim.x;
    float4 z = make_float4(0.f, 0.f, 0.f, 0.f);
    for (; i < total_q; i += stride) {
        long row = i >> 2;        // 4 float4 of packed counts per row
        long q = i & 3;
        out[row * 32 + q] = z;    // row stride = 128 floats = 32 float4
    }
}

// Per-edge scatter: packed u8 counts. counts[src][t] lives in u32 word
// (src*128 + t/4), byte t%4.
__global__ void count_kernel(const int* __restrict__ src,
                             const int* __restrict__ et,
                             unsigned* __restrict__ outw, int n_edge) {
    int i = blockIdx.x * blockDim.x + threadIdx.x;
    int stride = gridDim.x * blockDim.x;
    for (; i < n_edge; i += stride) {
        int s = src[i];
        int t = et[i];
        atomicAdd(outw + (size_t)s * D + (t >> 2), 1u << ((t & 3) * 8));
    }
}

// One wave (64 lanes) per entity. Lane l keeps rel[:, l] and rel[:, l+64] in
// registers (128 VGPR, protected by __launch_bounds__); counts broadcast via
// v_readlane (scalar pipe) instead of ds_bpermute.
__global__ __launch_bounds__(256, 1)
void finalize_kernel(float* __restrict__ out,
                     const float* __restrict__ rel,
                     const float* __restrict__ bias,
                     int n_ent) {
    const int lane = (int)(threadIdx.x & 63);
    const int wid = (int)((blockIdx.x * blockDim.x + threadIdx.x) >> 6);
    const int nw = (int)((gridDim.x * blockDim.x) >> 6);

    float ra[R], rb[R];
#pragma unroll
    for (int r = 0; r < R; ++r) {
        ra[r] = rel[r * D + lane];
        rb[r] = rel[r * D + 64 + lane];
    }
    const float ba = bias[lane];
    const float bb = bias[64 + lane];

    for (int e = wid; e < n_ent; e += nw) {
        float* row = out + (size_t)e * D;
        // lane l's count c[l] is byte (l&3) of packed word (l>>2)
        unsigned w = ((const unsigned*)row)[lane >> 2];
        float cl = (float)((w >> ((lane & 3) * 8)) & 0xffu);

        // deg = sum of 64 counts (butterfly reduce, 6 swizzles)
        float deg = cl;
#pragma unroll
        for (int off = 32; off; off >>= 1) deg += __shfl_xor(deg, off);

        // 4 independent FMA chains for latency hiding
        float a0 = 0.f, a1 = 0.f, a2 = 0.f, a3 = 0.f;
#pragma unroll
        for (int r = 0; r < R; r += 2) {
            float c0 = __int_as_float(__builtin_amdgcn_readlane(__float_as_int(cl), r));
            float c1 = __int_as_float(__builtin_amdgcn_readlane(__float_as_int(cl), r + 1));
            a0 = fmaf(c0, ra[r], a0);
            a1 = fmaf(c0, rb[r], a1);
            a2 = fmaf(c1, ra[r + 1], a2);
            a3 = fmaf(c1, rb[r + 1], a3);
        }
        float s = 1.0f / (deg + 1.0f);
        float y0 = fmaf(a0 + a2, s, ba);
        float y1 = fmaf(a1 + a3, s, bb);
        row[lane] = fmaxf(y0, 0.f);
        row[64 + lane] = fmaxf(y1, 0.f);
    }
}

extern "C" void kernel_launch(void* const* d_in, const int* in_sizes, int n_in,
                              void* d_out, int out_size, void* d_ws, size_t ws_size,
                              hipStream_t stream) {
    // inputs: 0=num_entities(scalar), 1=source, 2=edge_type, 3=rel_emb, 4=bias
    const int* src = (const int*)d_in[1];
    const int* et = (const int*)d_in[2];
    const float* rel = (const float*)d_in[3];
    const float* bias = (const float*)d_in[4];
    float* out = (float*)d_out;

    const int n_edge = in_sizes[1];
    const int n_ent = out_size / D;

    zero_counts_kernel<<<2048, 256, 0, stream>>>((float4*)out, (long)n_ent * 4);
    count_kernel<<<4096, 256, 0, stream>>>(src, et, (unsigned*)out, n_edge);
    finalize_kernel<<<2048, 256, 0, stream>>>(out, rel, bias, n_ent);
}

// Round 3
// 664.320 us; speedup vs baseline: 1.7620x; 1.2203x over previous
//
#include <hip/hip_runtime.h>

// Problem constants (from reference): D_IN = 128 outputs/row, N_REL = 64.
constexpr int D = 128;
constexpr int R = 64;

// --- Bucketed path constants ---
constexpr int SLICE_SHIFT = 9;           // 512 entities per bin
constexpr int SLICE = 1 << SLICE_SHIFT;
constexpr int CAP = 16384;               // records per bin (avg ~8.2k, sigma ~90)
constexpr int EPB = 16384;               // edges per phase-1 block
constexpr int NB_MAX = 1024;

__global__ void zero_fill_kernel(unsigned* __restrict__ p, int n) {
    int i = blockIdx.x * blockDim.x + threadIdx.x;
    if (i < n) p[i] = 0;
}

// Phase 1: compact edges into per-bin u16 records ((src&511)<<6 | rel).
// Global atomics only for per-(block,bin) reservations (~478k total, not 8M).
__global__ __launch_bounds__(256)
void bucket_kernel(const int* __restrict__ src, const int* __restrict__ et,
                   unsigned short* __restrict__ recs,
                   unsigned* __restrict__ bin_fill,
                   int n_edge, int nb) {
    __shared__ unsigned hist[NB_MAX];
    __shared__ unsigned base[NB_MAX];
    const int tid = threadIdx.x;
    for (int i = tid; i < nb; i += 256) hist[i] = 0;
    __syncthreads();

    const int e0 = blockIdx.x * EPB;
    const int e1 = min(e0 + EPB, n_edge);

    // Pass A: per-block bin histogram (LDS atomics).
    for (int e = e0 + tid; e < e1; e += 256) {
        int b = src[e] >> SLICE_SHIFT;
        atomicAdd(&hist[b], 1u);
    }
    __syncthreads();

    // Reserve global space per bin; reset hist to act as intra-block cursor.
    for (int i = tid; i < nb; i += 256) {
        unsigned c = hist[i];
        base[i] = c ? atomicAdd(&bin_fill[i], c) : 0u;
        hist[i] = 0;
    }
    __syncthreads();

    // Pass B: re-read edges (L2-hot) and scatter compacted records.
    for (int e = e0 + tid; e < e1; e += 256) {
        int s = src[e], t = et[e];
        int b = s >> SLICE_SHIFT;
        unsigned rec = ((unsigned)(s & (SLICE - 1)) << 6) | (unsigned)t;
        unsigned pos = base[b] + atomicAdd(&hist[b], 1u);
        if (pos < (unsigned)CAP)  // statistically impossible overflow; guards OOB
            recs[(size_t)b * CAP + pos] = (unsigned short)rec;
    }
}

// Phase 2 (fused): per-bin LDS packed-u8 histogram, then deg + counts@rel +
// bias + relu straight from LDS. One workgroup per bin, wave per 128 entities.
__global__ __launch_bounds__(256, 1)
void fused_kernel(const unsigned short* __restrict__ recs,
                  const unsigned* __restrict__ bin_fill,
                  const float* __restrict__ rel,
                  const float* __restrict__ bias,
                  float* __restrict__ out, int n_ent) {
    __shared__ unsigned pc[SLICE * 16];  // 512 entities x 64 u8 counts = 32 KB
    const int tid = threadIdx.x;
    const int lane = tid & 63;
    const int bin = blockIdx.x;

    for (int i = tid; i < SLICE * 16; i += 256) pc[i] = 0;

    // rel tile in registers while LDS zero settles: lane l holds rel[:,l], rel[:,l+64]
    float ra[R], rb[R];
#pragma unroll
    for (int r = 0; r < R; ++r) {
        ra[r] = rel[r * D + lane];
        rb[r] = rel[r * D + 64 + lane];
    }
    const float ba = bias[lane];
    const float bb = bias[64 + lane];
    __syncthreads();

    unsigned nrec = bin_fill[bin];
    if (nrec > (unsigned)CAP) nrec = CAP;
    const unsigned short* rp = recs + (size_t)bin * CAP;
    for (unsigned i = tid; i < nrec; i += 256) {
        unsigned rec = rp[i];
        unsigned le = rec >> 6, r = rec & 63u;
        atomicAdd(&pc[le * 16 + (r >> 2)], 1u << ((r & 3u) * 8));
    }
    __syncthreads();

    const int wv = tid >> 6;
    const int le0 = wv * (SLICE / 4), le1 = le0 + (SLICE / 4);
    for (int le = le0; le < le1; ++le) {
        int ent = bin * SLICE + le;
        if (ent >= n_ent) break;
        unsigned w = pc[le * 16 + (lane >> 2)];   // 4 lanes/word: broadcast, conflict-free
        float cl = (float)((w >> ((lane & 3) * 8)) & 0xffu);

        float deg = cl;
#pragma unroll
        for (int off = 32; off; off >>= 1) deg += __shfl_xor(deg, off);

        float a0 = 0.f, a1 = 0.f, a2 = 0.f, a3 = 0.f;
#pragma unroll
        for (int r = 0; r < R; r += 2) {
            float c0 = __int_as_float(__builtin_amdgcn_readlane(__float_as_int(cl), r));
            float c1 = __int_as_float(__builtin_amdgcn_readlane(__float_as_int(cl), r + 1));
            a0 = fmaf(c0, ra[r], a0);
            a1 = fmaf(c0, rb[r], a1);
            a2 = fmaf(c1, ra[r + 1], a2);
            a3 = fmaf(c1, rb[r + 1], a3);
        }
        float s = 1.0f / (deg + 1.0f);
        float* row = out + (size_t)ent * D;
        row[lane] = fmaxf(fmaf(a0 + a2, s, ba), 0.f);
        row[64 + lane] = fmaxf(fmaf(a1 + a3, s, bb), 0.f);
    }
}

// ---------------- Fallback path (round-2 pipeline, used if ws too small) ----
__global__ void zero_counts_kernel(float4* __restrict__ out, long total_q) {
    long i = (long)blockIdx.x * blockDim.x + threadIdx.x;
    long stride = (long)gridDim.x * blockDim.x;
    float4 z = make_float4(0.f, 0.f, 0.f, 0.f);
    for (; i < total_q; i += stride) {
        long row = i >> 2;
        long q = i & 3;
        out[row * 32 + q] = z;
    }
}

__global__ void count_kernel(const int* __restrict__ src,
                             const int* __restrict__ et,
                             unsigned* __restrict__ outw, int n_edge) {
    int i = blockIdx.x * blockDim.x + threadIdx.x;
    int stride = gridDim.x * blockDim.x;
    for (; i < n_edge; i += stride) {
        int s = src[i];
        int t = et[i];
        atomicAdd(outw + (size_t)s * D + (t >> 2), 1u << ((t & 3) * 8));
    }
}

__global__ __launch_bounds__(256, 1)
void finalize_kernel(float* __restrict__ out,
                     const float* __restrict__ rel,
                     const float* __restrict__ bias,
                     int n_ent) {
    const int lane = (int)(threadIdx.x & 63);
    const int wid = (int)((blockIdx.x * blockDim.x + threadIdx.x) >> 6);
    const int nw = (int)((gridDim.x * blockDim.x) >> 6);

    float ra[R], rb[R];
#pragma unroll
    for (int r = 0; r < R; ++r) {
        ra[r] = rel[r * D + lane];
        rb[r] = rel[r * D + 64 + lane];
    }
    const float ba = bias[lane];
    const float bb = bias[64 + lane];

    for (int e = wid; e < n_ent; e += nw) {
        float* row = out + (size_t)e * D;
        unsigned w = ((const unsigned*)row)[lane >> 2];
        float cl = (float)((w >> ((lane & 3) * 8)) & 0xffu);

        float deg = cl;
#pragma unroll
        for (int off = 32; off; off >>= 1) deg += __shfl_xor(deg, off);

        float a0 = 0.f, a1 = 0.f, a2 = 0.f, a3 = 0.f;
#pragma unroll
        for (int r = 0; r < R; r += 2) {
            float c0 = __int_as_float(__builtin_amdgcn_readlane(__float_as_int(cl), r));
            float c1 = __int_as_float(__builtin_amdgcn_readlane(__float_as_int(cl), r + 1));
            a0 = fmaf(c0, ra[r], a0);
            a1 = fmaf(c0, rb[r], a1);
            a2 = fmaf(c1, ra[r + 1], a2);
            a3 = fmaf(c1, rb[r + 1], a3);
        }
        float s = 1.0f / (deg + 1.0f);
        float y0 = fmaf(a0 + a2, s, ba);
        float y1 = fmaf(a1 + a3, s, bb);
        row[lane] = fmaxf(y0, 0.f);
        row[64 + lane] = fmaxf(y1, 0.f);
    }
}

extern "C" void kernel_launch(void* const* d_in, const int* in_sizes, int n_in,
                              void* d_out, int out_size, void* d_ws, size_t ws_size,
                              hipStream_t stream) {
    // inputs: 0=num_entities(scalar), 1=source, 2=edge_type, 3=rel_emb, 4=bias
    const int* src = (const int*)d_in[1];
    const int* et = (const int*)d_in[2];
    const float* rel = (const float*)d_in[3];
    const float* bias = (const float*)d_in[4];
    float* out = (float*)d_out;

    const int n_edge = in_sizes[1];
    const int n_ent = out_size / D;
    const int nb = (n_ent + SLICE - 1) >> SLICE_SHIFT;   // 977

    const size_t recs_bytes = (size_t)nb * CAP * sizeof(unsigned short);
    const size_t need = recs_bytes + (size_t)nb * sizeof(unsigned);

    if (nb <= NB_MAX && ws_size >= need) {
        unsigned short* recs = (unsigned short*)d_ws;
        unsigned* bin_fill = (unsigned*)((char*)d_ws + recs_bytes);

        zero_fill_kernel<<<(nb + 255) / 256, 256, 0, stream>>>(bin_fill, nb);
        bucket_kernel<<<(n_edge + EPB - 1) / EPB, 256, 0, stream>>>(
            src, et, recs, bin_fill, n_edge, nb);
        fused_kernel<<<nb, 256, 0, stream>>>(recs, bin_fill, rel, bias, out, n_ent);
    } else {
        zero_counts_kernel<<<2048, 256, 0, stream>>>((float4*)out, (long)n_ent * 4);
        count_kernel<<<4096, 256, 0, stream>>>(src, et, (unsigned*)out, n_edge);
        finalize_kernel<<<2048, 256, 0, stream>>>(out, rel, bias, n_ent);
    }
}

// Round 5
// 497.158 us; speedup vs baseline: 2.3544x; 1.3362x over previous
//
#include <hip/hip_runtime.h>

// Problem constants (from reference): D_IN = 128 outputs/row, N_REL = 64.
constexpr int D = 128;
constexpr int R = 64;

// --- Bucketed path constants ---
constexpr int SLICE_SHIFT = 9;           // 512 entities per bucket bin
constexpr int SLICE = 1 << SLICE_SHIFT;
constexpr int CAP = 16384;               // records per bin (avg ~8.2k, sigma ~90)
constexpr int EPB = 16384;               // edges per phase-1 block
constexpr int NB_MAX = 1024;
constexpr int PCW = 17;                  // padded u32 words per entity histogram row

typedef short bf16x8 __attribute__((ext_vector_type(8)));
typedef float f32x4 __attribute__((ext_vector_type(4)));

__device__ inline unsigned short f32_to_bf16_rne(float f) {
    unsigned b = __float_as_uint(f);
    b += 0x7fff + ((b >> 16) & 1);
    return (unsigned short)(b >> 16);
}

__global__ void zero_fill_kernel(unsigned* __restrict__ p, int n) {
    int i = blockIdx.x * blockDim.x + threadIdx.x;
    if (i < n) p[i] = 0;
}

// Phase 1: compact edges into per-bin u16 records ((src&511)<<6 | rel).
// Global atomics only for per-(block,bin) reservations (~478k total, not 8M).
__global__ __launch_bounds__(256)
void bucket_kernel(const int* __restrict__ src, const int* __restrict__ et,
                   unsigned short* __restrict__ recs,
                   unsigned* __restrict__ bin_fill,
                   int n_edge, int nb) {
    __shared__ unsigned hist[NB_MAX];
    __shared__ unsigned base[NB_MAX];
    const int tid = threadIdx.x;
    for (int i = tid; i < nb; i += 256) hist[i] = 0;
    __syncthreads();

    const int e0 = blockIdx.x * EPB;
    const int e1 = min(e0 + EPB, n_edge);

    for (int e = e0 + tid; e < e1; e += 256) {
        int b = src[e] >> SLICE_SHIFT;
        atomicAdd(&hist[b], 1u);
    }
    __syncthreads();

    for (int i = tid; i < nb; i += 256) {
        unsigned c = hist[i];
        base[i] = c ? atomicAdd(&bin_fill[i], c) : 0u;
        hist[i] = 0;
    }
    __syncthreads();

    for (int e = e0 + tid; e < e1; e += 256) {
        int s = src[e], t = et[e];
        int b = s >> SLICE_SHIFT;
        unsigned rec = ((unsigned)(s & (SLICE - 1)) << 6) | (unsigned)t;
        unsigned pos = base[b] + atomicAdd(&hist[b], 1u);
        if (pos < (unsigned)CAP)
            recs[(size_t)b * CAP + pos] = (unsigned short)rec;
    }
}

// Phase 2 (fused, MFMA): one block per HALF-bin (256 entities).
// LDS: padded u8 histogram (17.4 KB) + bf16 A tiles (32 KB) + deg_inv (1 KB).
// A LDS layout: [mtile(16)][kstep(2)][kgroup(4)][row(16)][8 bf16] — the MFMA
// read at lane l is byte-contiguous (addr = m*2048 + s*1024 + l*16): conflict-free.
__global__ __launch_bounds__(256, 3)
void fused_mfma_kernel(const unsigned short* __restrict__ recs,
                       const unsigned* __restrict__ bin_fill,
                       const float* __restrict__ rel,
                       const float* __restrict__ bias,
                       float* __restrict__ out, int n_ent) {
    __shared__ unsigned pc[256 * PCW];   // 17.4 KB packed u8 counts
    __shared__ unsigned Abuf[16 * 512];  // 32 KB bf16 A tiles (u32 words)
    __shared__ float dinv[256];          // 1/(deg+1)

    const int tid = threadIdx.x;
    const int lane = tid & 63;
    const int wave = tid >> 6;
    const int bin = blockIdx.x >> 1;
    const int half = blockIdx.x & 1;
    const int ent0 = bin * SLICE + half * 256;
    const int l15 = lane & 15, lhi = lane >> 4;

    for (int i = tid; i < 256 * PCW; i += 256) pc[i] = 0;

    // B fragments (rel as bf16) + bias columns in registers. rel is 32 KB,
    // L2/L3-hot across all blocks. B[k][n]: col=lane&15, k=(lane>>4)*8+j.
    bf16x8 Bf[2][8];
#pragma unroll
    for (int s = 0; s < 2; ++s)
#pragma unroll
        for (int t = 0; t < 8; ++t) {
            union { bf16x8 v; unsigned short u[8]; } tmp;
#pragma unroll
            for (int j = 0; j < 8; ++j)
                tmp.u[j] = f32_to_bf16_rne(rel[(s * 32 + lhi * 8 + j) * D + t * 16 + l15]);
            Bf[s][t] = tmp.v;
        }
    float bcol[8];
#pragma unroll
    for (int t = 0; t < 8; ++t) bcol[t] = bias[t * 16 + l15];
    __syncthreads();

    // Histogram this half-bin's records via LDS atomics.
    unsigned nrec = bin_fill[bin];
    if (nrec > (unsigned)CAP) nrec = CAP;
    const unsigned short* rp = recs + (size_t)bin * CAP;
    for (unsigned i = tid; i < nrec; i += 256) {
        unsigned rec = rp[i];
        if (((rec >> 14) & 1u) == (unsigned)half) {
            unsigned le = (rec >> 6) & 255u, r = rec & 63u;
            atomicAdd(&pc[le * PCW + (r >> 2)], 1u << ((r & 3u) * 8));
        }
    }
    __syncthreads();

    // Per-entity: deg + u8 -> bf16 A-tile build (all indices compile-time).
    {
        const int e = tid;
        unsigned cw[32];
        unsigned degs = 0;
#pragma unroll
        for (int w = 0; w < 16; ++w) {
            unsigned v = pc[e * PCW + w];
            unsigned b0 = v & 0xffu, b1 = (v >> 8) & 0xffu;
            unsigned b2 = (v >> 16) & 0xffu, b3 = v >> 24;
            degs += b0 + b1 + b2 + b3;
            // bf16 of small ints is exact: take high 16 bits of the f32.
            cw[2 * w] = (__float_as_uint((float)b0) >> 16) |
                        (__float_as_uint((float)b1) & 0xffff0000u);
            cw[2 * w + 1] = (__float_as_uint((float)b2) >> 16) |
                            (__float_as_uint((float)b3) & 0xffff0000u);
        }
        dinv[e] = 1.0f / ((float)degs + 1.0f);
        const int mt = e >> 4, row = e & 15;
#pragma unroll
        for (int s = 0; s < 2; ++s)
#pragma unroll
            for (int g = 0; g < 4; ++g) {
                int idx = mt * 512 + s * 256 + g * 64 + row * 4;
                int ci = s * 16 + g * 4;
                *(uint4*)&Abuf[idx] = make_uint4(cw[ci], cw[ci + 1], cw[ci + 2], cw[ci + 3]);
            }
    }
    __syncthreads();

    // MFMA: each wave owns 4 mtiles (16 rows each). K=64 = 2 MFMA K-steps.
#pragma unroll
    for (int mi = 0; mi < 4; ++mi) {
        const int m = wave * 4 + mi;
        bf16x8 a0 = *(const bf16x8*)&Abuf[m * 512 + 0 + lane * 4];
        bf16x8 a1 = *(const bf16x8*)&Abuf[m * 512 + 256 + lane * 4];
        f32x4 acc[8];
#pragma unroll
        for (int t = 0; t < 8; ++t) {
            acc[t] = (f32x4){0.f, 0.f, 0.f, 0.f};
            acc[t] = __builtin_amdgcn_mfma_f32_16x16x32_bf16(a0, Bf[0][t], acc[t], 0, 0, 0);
            acc[t] = __builtin_amdgcn_mfma_f32_16x16x32_bf16(a1, Bf[1][t], acc[t], 0, 0, 0);
        }
        f32x4 dv = *(const f32x4*)&dinv[m * 16 + lhi * 4];
        const int rowbase = ent0 + m * 16 + lhi * 4;
#pragma unroll
        for (int j = 0; j < 4; ++j) {
            int ent = rowbase + j;
            if (ent < n_ent) {
                float* op = out + (size_t)ent * D + l15;
#pragma unroll
                for (int t = 0; t < 8; ++t) {
                    float v = fmaf(acc[t][j], dv[j], bcol[t]);
                    op[t * 16] = fmaxf(v, 0.f);
                }
            }
        }
    }
}

// ---------------- Fallback path (round-2 pipeline, used if ws too small) ----
__global__ void zero_counts_kernel(float4* __restrict__ out, long total_q) {
    long i = (long)blockIdx.x * blockDim.x + threadIdx.x;
    long stride = (long)gridDim.x * blockDim.x;
    float4 z = make_float4(0.f, 0.f, 0.f, 0.f);
    for (; i < total_q; i += stride) {
        long row = i >> 2;
        long q = i & 3;
        out[row * 32 + q] = z;
    }
}

__global__ void count_kernel(const int* __restrict__ src,
                             const int* __restrict__ et,
                             unsigned* __restrict__ outw, int n_edge) {
    int i = blockIdx.x * blockDim.x + threadIdx.x;
    int stride = gridDim.x * blockDim.x;
    for (; i < n_edge; i += stride) {
        int s = src[i];
        int t = et[i];
        atomicAdd(outw + (size_t)s * D + (t >> 2), 1u << ((t & 3) * 8));
    }
}

__global__ __launch_bounds__(256, 1)
void finalize_kernel(float* __restrict__ out,
                     const float* __restrict__ rel,
                     const float* __restrict__ bias,
                     int n_ent) {
    const int lane = (int)(threadIdx.x & 63);
    const int wid = (int)((blockIdx.x * blockDim.x + threadIdx.x) >> 6);
    const int nw = (int)((gridDim.x * blockDim.x) >> 6);

    float ra[R], rb[R];
#pragma unroll
    for (int r = 0; r < R; ++r) {
        ra[r] = rel[r * D + lane];
        rb[r] = rel[r * D + 64 + lane];
    }
    const float ba = bias[lane];
    const float bb = bias[64 + lane];

    for (int e = wid; e < n_ent; e += nw) {
        float* row = out + (size_t)e * D;
        unsigned w = ((const unsigned*)row)[lane >> 2];
        float cl = (float)((w >> ((lane & 3) * 8)) & 0xffu);

        float deg = cl;
#pragma unroll
        for (int off = 32; off; off >>= 1) deg += __shfl_xor(deg, off);

        float a0 = 0.f, a1 = 0.f, a2 = 0.f, a3 = 0.f;
#pragma unroll
        for (int r = 0; r < R; r += 2) {
            float c0 = __int_as_float(__builtin_amdgcn_readlane(__float_as_int(cl), r));
            float c1 = __int_as_float(__builtin_amdgcn_readlane(__float_as_int(cl), r + 1));
            a0 = fmaf(c0, ra[r], a0);
            a1 = fmaf(c0, rb[r], a1);
            a2 = fmaf(c1, ra[r + 1], a2);
            a3 = fmaf(c1, rb[r + 1], a3);
        }
        float s = 1.0f / (deg + 1.0f);
        float y0 = fmaf(a0 + a2, s, ba);
        float y1 = fmaf(a1 + a3, s, bb);
        row[lane] = fmaxf(y0, 0.f);
        row[64 + lane] = fmaxf(y1, 0.f);
    }
}

extern "C" void kernel_launch(void* const* d_in, const int* in_sizes, int n_in,
                              void* d_out, int out_size, void* d_ws, size_t ws_size,
                              hipStream_t stream) {
    // inputs: 0=num_entities(scalar), 1=source, 2=edge_type, 3=rel_emb, 4=bias
    const int* src = (const int*)d_in[1];
    const int* et = (const int*)d_in[2];
    const float* rel = (const float*)d_in[3];
    const float* bias = (const float*)d_in[4];
    float* out = (float*)d_out;

    const int n_edge = in_sizes[1];
    const int n_ent = out_size / D;
    const int nb = (n_ent + SLICE - 1) >> SLICE_SHIFT;   // 977

    const size_t recs_bytes = (size_t)nb * CAP * sizeof(unsigned short);
    const size_t need = recs_bytes + (size_t)nb * sizeof(unsigned);

    if (nb <= NB_MAX && ws_size >= need) {
        unsigned short* recs = (unsigned short*)d_ws;
        unsigned* bin_fill = (unsigned*)((char*)d_ws + recs_bytes);

        zero_fill_kernel<<<(nb + 255) / 256, 256, 0, stream>>>(bin_fill, nb);
        bucket_kernel<<<(n_edge + EPB - 1) / EPB, 256, 0, stream>>>(
            src, et, recs, bin_fill, n_edge, nb);
        fused_mfma_kernel<<<nb * 2, 256, 0, stream>>>(recs, bin_fill, rel, bias, out, n_ent);
    } else {
        zero_counts_kernel<<<2048, 256, 0, stream>>>((float4*)out, (long)n_ent * 4);
        count_kernel<<<4096, 256, 0, stream>>>(src, et, (unsigned*)out, n_edge);
        finalize_kernel<<<2048, 256, 0, stream>>>(out, rel, bias, n_ent);
    }
}